// Round 3
// baseline (187.303 us; speedup 1.0000x reference)
//
#include <hip/hip_runtime.h>

// n_class=32, n_support=16, D=1024; Q = 512 query rows. Output (512,32,1024) fp32.
// VALU/transcendental-bound: 268M tanh evals, each = mul + exp2 + add + rcp + add.
// No LDS: support class (64 KB) is served from L1/L2; LDS staging capped occupancy
// at 2 waves/SIMD in R1 (OccupancyPercent=20, VALUBusy=66 -> latency-bound).
constexpr int NC = 32, NS = 16, NQ = 512, D = 1024;
constexpr int QPW = 4;              // queries per wave (amortize each support load 4x)
constexpr int WPB = 4;              // waves per block (256 threads)
constexpr int QPB = QPW * WPB;      // 16 queries per block

typedef float vfloat4 __attribute__((ext_vector_type(4)));  // native vector: OK for nontemporal builtins

__global__ __launch_bounds__(256)
void proto_attn_kernel(const float* __restrict__ data, float* __restrict__ out) {
    const int c    = blockIdx.x;    // class
    const int qt   = blockIdx.y;    // query tile
    const int tid  = threadIdx.x;
    const int wave = tid >> 6;
    const int lane = tid & 63;

    // tanh(x) = 1 - 2/(exp2(K*x)+1),  K = 2*log2(e)
    const float Kc  = 2.88539008177792681472f;
    const float L2E = 1.44269504088896340736f;

    const int q0 = qt * QPB + wave * QPW;

    // ---- load 4 query rows into registers, pre-scaled by K ----
    vfloat4 q[QPW][4];
    #pragma unroll
    for (int qi = 0; qi < QPW; ++qi) {
        const vfloat4* qg = reinterpret_cast<const vfloat4*>(
            data + (size_t)(NC * NS + q0 + qi) * D);
        #pragma unroll
        for (int j = 0; j < 4; ++j) {
            vfloat4 t = qg[lane + 64 * j];
            q[qi][j] = t * Kc;
        }
    }

    const vfloat4* sup = reinterpret_cast<const vfloat4*>(data + (size_t)c * NS * D);

    // ---- scores: sc[qi][s] = D - 2 * sum_d sigmoid-like term ----
    float sc[QPW][NS];
    #pragma unroll 4
    for (int s = 0; s < NS; ++s) {
        float r[QPW] = {0.f, 0.f, 0.f, 0.f};
        #pragma unroll
        for (int j = 0; j < 4; ++j) {
            const vfloat4 sv = sup[s * (D / 4) + lane + 64 * j];
            #pragma unroll
            for (int qi = 0; qi < QPW; ++qi) {
                r[qi] += __builtin_amdgcn_rcpf(__builtin_amdgcn_exp2f(sv.x * q[qi][j].x) + 1.f);
                r[qi] += __builtin_amdgcn_rcpf(__builtin_amdgcn_exp2f(sv.y * q[qi][j].y) + 1.f);
                r[qi] += __builtin_amdgcn_rcpf(__builtin_amdgcn_exp2f(sv.z * q[qi][j].z) + 1.f);
                r[qi] += __builtin_amdgcn_rcpf(__builtin_amdgcn_exp2f(sv.w * q[qi][j].w) + 1.f);
            }
        }
        // wave64 butterfly reduction over d
        #pragma unroll
        for (int m = 32; m >= 1; m >>= 1) {
            #pragma unroll
            for (int qi = 0; qi < QPW; ++qi)
                r[qi] += __shfl_xor(r[qi], m, 64);
        }
        #pragma unroll
        for (int qi = 0; qi < QPW; ++qi)
            sc[qi][s] = (float)D - 2.f * r[qi];
    }

    // ---- softmax over s (replicated per lane), fold normalization into sc ----
    #pragma unroll
    for (int qi = 0; qi < QPW; ++qi) {
        float m = sc[qi][0];
        #pragma unroll
        for (int s = 1; s < NS; ++s) m = fmaxf(m, sc[qi][s]);
        float sum = 0.f;
        #pragma unroll
        for (int s = 0; s < NS; ++s) {
            sc[qi][s] = __builtin_amdgcn_exp2f((sc[qi][s] - m) * L2E);
            sum += sc[qi][s];
        }
        const float inv = __builtin_amdgcn_rcpf(sum);
        #pragma unroll
        for (int s = 0; s < NS; ++s) sc[qi][s] *= inv;
    }

    // ---- proto: out[q,c,:] = sum_s att[s] * support[c,s,:] ----
    vfloat4 acc[QPW][4];
    #pragma unroll
    for (int qi = 0; qi < QPW; ++qi)
        #pragma unroll
        for (int j = 0; j < 4; ++j)
            acc[qi][j] = (vfloat4)(0.f);

    #pragma unroll 4
    for (int s = 0; s < NS; ++s) {
        #pragma unroll
        for (int j = 0; j < 4; ++j) {
            const vfloat4 sv = sup[s * (D / 4) + lane + 64 * j];
            #pragma unroll
            for (int qi = 0; qi < QPW; ++qi) {
                acc[qi][j].x = fmaf(sc[qi][s], sv.x, acc[qi][j].x);
                acc[qi][j].y = fmaf(sc[qi][s], sv.y, acc[qi][j].y);
                acc[qi][j].z = fmaf(sc[qi][s], sv.z, acc[qi][j].z);
                acc[qi][j].w = fmaf(sc[qi][s], sv.w, acc[qi][j].w);
            }
        }
    }

    // nontemporal stores: 64 MB output stream should not evict the 4 MB input
    #pragma unroll
    for (int qi = 0; qi < QPW; ++qi) {
        vfloat4* og = reinterpret_cast<vfloat4*>(out + ((size_t)(q0 + qi) * NC + c) * D);
        #pragma unroll
        for (int j = 0; j < 4; ++j)
            __builtin_nontemporal_store(acc[qi][j], og + lane + 64 * j);
    }
}

extern "C" void kernel_launch(void* const* d_in, const int* in_sizes, int n_in,
                              void* d_out, int out_size, void* d_ws, size_t ws_size,
                              hipStream_t stream) {
    (void)in_sizes; (void)n_in; (void)out_size; (void)d_ws; (void)ws_size;
    const float* data = (const float*)d_in[0];
    float* out = (float*)d_out;
    dim3 grid(NC, NQ / QPB);   // 32 classes x 32 query tiles = 1024 blocks
    proto_attn_kernel<<<grid, dim3(256), 0, stream>>>(data, out);
}